// Round 5
// baseline (176.559 us; speedup 1.0000x reference)
//
#include <hip/hip_runtime.h>
#include <hip/hip_bf16.h>

#define BB 8
#define LL 4096
#define NCH 8192
#define IDIM 256
#define KDIM 512
#define ODIM 512
#define NDIR 6
#define TOT (BB * LL)  // 32768

typedef short short8 __attribute__((ext_vector_type(8)));
typedef float floatx4 __attribute__((ext_vector_type(4)));

// ws layout (ints unless noted):
//   [0..7]                      cnt per dir (atomic cursors)
//   [64 .. 64+TOT)              slot_of[token]
//   [64+TOT .. 64+2T)           rows_of[token] (r0 | r1<<16)
//   [IDX_OFF .. IDX_OFF+6T)     idx[slot] -> token
//   bf16 packedA[NDIR*TOT][512] (bucket-ordered [a|b] rows)  ~201 MB
//   bf16 W_bf[NDIR*ODIM*KDIM]   ~3.1 MB
// total ~= 206 MB (ws is 268 MB per observed poison fills)
#define IDX_OFF (64 + 2 * TOT)
#define PACKA_OFF_INTS (64 + (2 + NDIR) * TOT)
#define PACKA_ELEMS ((long long)NDIR * TOT * KDIM)
#define W_ELEMS (NDIR * ODIM * KDIM)  // 1,572,864
#define N_W8 (W_ELEMS / 8)            // 196,608

__device__ inline void async_copy16(const void* g, void* l) {
  __builtin_amdgcn_global_load_lds(
      (const __attribute__((address_space(1))) void*)g,
      (__attribute__((address_space(3))) void*)l, 16, 0, 0);
}

// ---- Kernel 1: bucket tokens (count+scatter fused; bases are d*TOT) ----
__global__ __launch_bounds__(256) void scatter_kernel(
    const int* __restrict__ vec, const int* __restrict__ child_l,
    const int* __restrict__ child_r, const int* __restrict__ drev,
    const int* __restrict__ dmap, int* __restrict__ ws) {
  __shared__ int lcnt[8];
  __shared__ int gbase[8];
  int tid = threadIdx.x;
  if (tid < 8) lcnt[tid] = 0;
  __syncthreads();

  int lin = blockIdx.x * 256 + tid;
  int l = lin & (LL - 1);
  int v = vec[lin];
  int dir = dmap[v] & 7;
  int sw = drev[v];
  int cl = child_l[l];
  int cr = child_r[l];
  int r0 = sw ? cr : cl;  // first half of x
  int r1 = sw ? cl : cr;  // second half
  int pos = atomicAdd(&lcnt[dir], 1);
  __syncthreads();
  if (tid < 8) gbase[tid] = lcnt[tid] ? atomicAdd(&ws[tid], lcnt[tid]) : 0;
  __syncthreads();
  int slot = dir * TOT + gbase[dir] + pos;
  ws[64 + lin] = slot;
  ws[64 + TOT + lin] = r0 | (r1 << 16);
}

// ---- Kernel 2: pack A (gather+swap+cvt, bucket-ordered) + cvt(W) ----
__global__ __launch_bounds__(256) void pack_kernel(
    const float* __restrict__ last, const float* __restrict__ W,
    int* __restrict__ ws) {
  __hip_bfloat16* packedA = (__hip_bfloat16*)(ws + PACKA_OFF_INTS);
  __hip_bfloat16* W_bf = packedA + PACKA_ELEMS;
  int bid = blockIdx.x;
  if (bid < TOT / 4) {
    int tid = threadIdx.x;
    int t = bid * 4 + (tid >> 6);
    int L = tid & 63;
    int slot = ws[64 + t];
    int rr = ws[64 + TOT + t];
    int b = t >> 12;  // L=4096
    int r = (L < 32) ? (rr & (NCH - 1)) : ((rr >> 16) & (NCH - 1));
    const floatx4* src =
        (const floatx4*)(last + (long long)(b * NCH + r) * IDIM) + (L & 31) * 2;
    floatx4 x0 = src[0];
    floatx4 x1 = src[1];
    union { short8 v; __hip_bfloat16 h[8]; } u;
    u.h[0] = __float2bfloat16(x0[0]); u.h[1] = __float2bfloat16(x0[1]);
    u.h[2] = __float2bfloat16(x0[2]); u.h[3] = __float2bfloat16(x0[3]);
    u.h[4] = __float2bfloat16(x1[0]); u.h[5] = __float2bfloat16(x1[1]);
    u.h[6] = __float2bfloat16(x1[2]); u.h[7] = __float2bfloat16(x1[3]);
    ((short8*)(packedA + (long long)slot * KDIM + (L >> 5) * IDIM))[L & 31] = u.v;
    if (L == 0) ws[IDX_OFF + slot] = t;
  } else {
    int gid = (bid - TOT / 4) * 256 + threadIdx.x;  // < N_W8
    const floatx4* s = (const floatx4*)W;
    floatx4 a = s[2 * gid];
    floatx4 b = s[2 * gid + 1];
    union { short8 v; __hip_bfloat16 h[8]; } u;
    u.h[0] = __float2bfloat16(a[0]); u.h[1] = __float2bfloat16(a[1]);
    u.h[2] = __float2bfloat16(a[2]); u.h[3] = __float2bfloat16(a[3]);
    u.h[4] = __float2bfloat16(b[0]); u.h[5] = __float2bfloat16(b[1]);
    u.h[6] = __float2bfloat16(b[2]); u.h[7] = __float2bfloat16(b[3]);
    ((short8*)W_bf)[gid] = u.v;
  }
}

// ---- Kernel 3: grouped GEMM, 128x128 tile, BK=32 double-buffered LDS ----
// 4 waves (2x2), wave 64x64 via 4x4 mfma_f32_16x16x32_bf16.
// LDS rows of 32 elems (64 B = 4x16B units); unit swizzle u_stored = u ^ ((row>>1)&3)
// -> every bank exactly 2-way across a quad's 16 lanes (free, m136).
__global__ __launch_bounds__(256) void gemm_kernel(
    const float* __restrict__ bias, const float* __restrict__ alpha_m,
    const int* __restrict__ ws, float* __restrict__ out) {
  __shared__ __hip_bfloat16 Als[2][128 * 32];  // 8 KB x2
  __shared__ __hip_bfloat16 Bls[2][128 * 32];  // 8 KB x2

  // tile -> dir map from per-dir counts (128-aligned tile ranges)
  const int mt = blockIdx.y;
  const int nt = blockIdx.x;
  int d = -1, count = 0, m_base = 0;
  {
    int tb = 0;
    for (int dd = 0; dd < NDIR; ++dd) {
      int c = ws[dd];
      int ntile = (c + 127) >> 7;
      if (mt < tb + ntile) { d = dd; count = c; m_base = (mt - tb) * 128; break; }
      tb += ntile;
    }
  }
  if (d < 0) return;

  const __hip_bfloat16* packedA = (const __hip_bfloat16*)(ws + PACKA_OFF_INTS);
  const __hip_bfloat16* W_bf = packedA + PACKA_ELEMS;

  const int tid = threadIdx.x;
  const int wave = __builtin_amdgcn_readfirstlane(tid >> 6);
  const int lane = tid & 63;
  const int lane15 = lane & 15;
  const int quad = lane >> 4;
  const int wm = wave >> 1;
  const int wn = wave & 1;
  const int n_blk = nt * 128;

  // staging: per wave 2 A-instrs + 2 B-instrs, 16 rows (16B/lane) each
  const __hip_bfloat16* pa[2];
  const __hip_bfloat16* pb[2];
  int ldsbase[2];
  {
    int f = (lane >> 3) & 3;          // (sr>>1)&3 for sr = 16*m + (lane>>2)
    int su = ((lane & 3) ^ f) * 8;    // swizzled source unit -> elem offset
#pragma unroll
    for (int i = 0; i < 2; ++i) {
      int sr = wave * 32 + i * 16 + (lane >> 2);  // local row 0..127
      ldsbase[i] = (wave * 32 + i * 16) * 32;     // elems (wave-uniform)
      int lr = m_base + sr;
      if (lr >= count) lr = count - 1;
      pa[i] = packedA + (long long)(d * TOT + lr) * KDIM + su;
      pb[i] = W_bf + (long long)(d * ODIM + n_blk + sr) * KDIM + su;
    }
  }

  floatx4 acc[4][4] = {};
  const int xq = (lane15 >> 1) & 3;  // frag-read swizzle key ((row>>1)&3)
  const int xcol = (quad ^ xq) * 8;

  // prologue: stage chunk 0 into buf 0
#pragma unroll
  for (int i = 0; i < 2; ++i) {
    async_copy16(pa[i], &Als[0][ldsbase[i]]);
    async_copy16(pb[i], &Bls[0][ldsbase[i]]);
  }

#pragma unroll
  for (int kt = 0; kt < 16; ++kt) {
    __syncthreads();  // chunk kt staged & visible; prior reads drained
    if (kt < 15) {
      const int nb = (kt + 1) & 1;
      const int ko = (kt + 1) * 32;
#pragma unroll
      for (int i = 0; i < 2; ++i) {
        async_copy16(pa[i] + ko, &Als[nb][ldsbase[i]]);
        async_copy16(pb[i] + ko, &Bls[nb][ldsbase[i]]);
      }
    }
    const int c = kt & 1;
    short8 a[4], b[4];
#pragma unroll
    for (int i = 0; i < 4; ++i)
      a[i] = *(const short8*)&Als[c][(wm * 64 + i * 16 + lane15) * 32 + xcol];
#pragma unroll
    for (int j = 0; j < 4; ++j)
      b[j] = *(const short8*)&Bls[c][(wn * 64 + j * 16 + lane15) * 32 + xcol];
#pragma unroll
    for (int i = 0; i < 4; ++i)
#pragma unroll
      for (int j = 0; j < 4; ++j)
        acc[i][j] = __builtin_amdgcn_mfma_f32_16x16x32_bf16(a[i], b[j], acc[i][j], 0, 0, 0);
  }

  // epilogue: bias + leaky relu, scatter rows by token
  const float alpha = alpha_m[d];
  float bj[4];
#pragma unroll
  for (int j = 0; j < 4; ++j)
    bj[j] = bias[d * ODIM + n_blk + wn * 64 + j * 16 + lane15];

#pragma unroll
  for (int i = 0; i < 4; ++i) {
#pragma unroll
    for (int reg = 0; reg < 4; ++reg) {
      int row_id = m_base + wm * 64 + i * 16 + quad * 4 + reg;
      if (row_id >= count) continue;
      int t = ws[IDX_OFF + d * TOT + row_id] & (TOT - 1);
      float* orow = out + (long long)t * ODIM + n_blk + wn * 64;
#pragma unroll
      for (int j = 0; j < 4; ++j) {
        float y = acc[i][j][reg] + bj[j];
        y = y > 0.f ? y : alpha * y;
        orow[j * 16 + lane15] = y;
      }
    }
  }
}

extern "C" void kernel_launch(void* const* d_in, const int* in_sizes, int n_in,
                              void* d_out, int out_size, void* d_ws, size_t ws_size,
                              hipStream_t stream) {
  const float* last = (const float*)d_in[0];
  const float* W = (const float*)d_in[1];
  const float* bias = (const float*)d_in[2];
  const float* alpha = (const float*)d_in[3];
  const int* child_l = (const int*)d_in[4];
  const int* child_r = (const int*)d_in[5];
  const int* vec = (const int*)d_in[6];
  const int* drev = (const int*)d_in[7];
  const int* dmap = (const int*)d_in[8];

  int* ws = (int*)d_ws;

  hipMemsetAsync(ws, 0, 64 * sizeof(int), stream);
  scatter_kernel<<<TOT / 256, 256, 0, stream>>>(vec, child_l, child_r, drev, dmap, ws);
  pack_kernel<<<TOT / 4 + N_W8 / 256, 256, 0, stream>>>(last, W, ws);
  dim3 grid(ODIM / 128, TOT / 128 + NDIR, 1);
  gemm_kernel<<<grid, 256, 0, stream>>>(bias, alpha, ws, (float*)d_out);
}

// Round 6
// 173.463 us; speedup vs baseline: 1.0178x; 1.0178x over previous
//
#include <hip/hip_runtime.h>
#include <hip/hip_bf16.h>

#define BB 8
#define LL 4096
#define NCH 8192
#define IDIM 256
#define KDIM 512
#define ODIM 512
#define NDIR 6
#define TOT (BB * LL)  // 32768
#define MT 64          // m-tile rows

typedef short short8 __attribute__((ext_vector_type(8)));
typedef float floatx4 __attribute__((ext_vector_type(4)));

// ws layout (ints):
//   [0..7]                          cnt per dir (atomic cursors)
//   [64 .. 64+6T)                   idx_by_slot  (slot -> token), slot = d*TOT + pos
//   [64+6T .. 64+12T)               rows_by_slot (r0 | r1<<16)
//   then bf16 last copy (33.5 MB), bf16 W copy (3.1 MB)   => ~38 MB total
#define IDX_OFF 64
#define ROWS_OFF (64 + NDIR * TOT)
#define LASTBF_OFF (64 + 2 * NDIR * TOT)
#define LAST_ELEMS (BB * NCH * IDIM)  // 16,777,216
#define W_ELEMS (NDIR * ODIM * KDIM)  // 1,572,864
#define N_LAST8 (LAST_ELEMS / 8)      // 2,097,152
#define N_W8 (W_ELEMS / 8)            // 196,608

__device__ inline void async_copy16(const void* g, void* l) {
  __builtin_amdgcn_global_load_lds(
      (const __attribute__((address_space(1))) void*)g,
      (__attribute__((address_space(3))) void*)l, 16, 0, 0);
}

__device__ inline void cvt8(const float* __restrict__ src,
                            __hip_bfloat16* __restrict__ dst, int i) {
  const floatx4* s = (const floatx4*)src;
  floatx4 a = s[2 * i];
  floatx4 b = s[2 * i + 1];
  union { short8 v; __hip_bfloat16 h[8]; } u;
  u.h[0] = __float2bfloat16(a[0]); u.h[1] = __float2bfloat16(a[1]);
  u.h[2] = __float2bfloat16(a[2]); u.h[3] = __float2bfloat16(a[3]);
  u.h[4] = __float2bfloat16(b[0]); u.h[5] = __float2bfloat16(b[1]);
  u.h[6] = __float2bfloat16(b[2]); u.h[7] = __float2bfloat16(b[3]);
  ((short8*)dst)[i] = u.v;
}

// ---- Kernel 1: bucket tokens (count+scatter fused; bucket base d*TOT) ----
__global__ __launch_bounds__(256) void scatter_kernel(
    const int* __restrict__ vec, const int* __restrict__ child_l,
    const int* __restrict__ child_r, const int* __restrict__ drev,
    const int* __restrict__ dmap, int* __restrict__ ws) {
  __shared__ int lcnt[8];
  __shared__ int gbase[8];
  int tid = threadIdx.x;
  if (tid < 8) lcnt[tid] = 0;
  __syncthreads();

  int t = blockIdx.x * 256 + tid;
  int l = t & (LL - 1);
  int v = vec[t];
  int dir = dmap[v] & 7;
  int sw = drev[v];
  int cl = child_l[l];
  int cr = child_r[l];
  int r0 = sw ? cr : cl;  // first half of x
  int r1 = sw ? cl : cr;  // second half
  int pos = atomicAdd(&lcnt[dir], 1);
  __syncthreads();
  if (tid < 8) gbase[tid] = lcnt[tid] ? atomicAdd(&ws[tid], lcnt[tid]) : 0;
  __syncthreads();
  int slot = dir * TOT + gbase[dir] + pos;
  ws[IDX_OFF + slot] = t;
  ws[ROWS_OFF + slot] = r0 | (r1 << 16);
}

// ---- Kernel 2: pure cvt fp32->bf16 (last, then W) ----
__global__ __launch_bounds__(256) void prep_kernel(
    const float* __restrict__ last, const float* __restrict__ W,
    int* __restrict__ ws) {
  __hip_bfloat16* last_bf = (__hip_bfloat16*)(ws + LASTBF_OFF);
  __hip_bfloat16* W_bf = last_bf + LAST_ELEMS;
  int gid = blockIdx.x * 256 + threadIdx.x;
  if (gid < N_LAST8) cvt8(last, last_bf, gid);
  else cvt8(W, W_bf, gid - N_LAST8);
}

// ---- Kernel 3: grouped GEMM, 64x128 tile, BK=32 double-buffered LDS ----
// 4 waves (2m x 2n): wave-tile 32x64 -> acc[2][4] of mfma_f32_16x16x32_bf16.
// LDS rows of 32 elems (4 x 16B units); stored[row][u] = global[row][u ^ ((row>>1)&3)]
// -> every ds_read_b128 quad-group hits each bank-span exactly 2x (free, m136).
__global__ __launch_bounds__(256) void gemm_kernel(
    const float* __restrict__ bias, const float* __restrict__ alpha_m,
    const int* __restrict__ ws, float* __restrict__ out) {
  __shared__ __hip_bfloat16 Als[2][MT * 32];    // 4 KB x2
  __shared__ __hip_bfloat16 Bls[2][128 * 32];   // 8 KB x2  (24 KB total)

  // tile -> (dir, m_base) from per-dir counts (64-aligned tile ranges)
  const int mt = blockIdx.y;
  const int nt = blockIdx.x;
  int d = -1, count = 0, m_base = 0;
  {
    int tb = 0;
    for (int dd = 0; dd < NDIR; ++dd) {
      int c = ws[dd];
      int ntile = (c + MT - 1) / MT;
      if (mt < tb + ntile) { d = dd; count = c; m_base = (mt - tb) * MT; break; }
      tb += ntile;
    }
  }
  if (d < 0) return;

  const __hip_bfloat16* last_bf = (const __hip_bfloat16*)(ws + LASTBF_OFF);
  const __hip_bfloat16* W_bf = last_bf + LAST_ELEMS;
  const int* idx = ws + IDX_OFF + d * TOT;
  const int* rows = ws + ROWS_OFF + d * TOT;

  const int tid = threadIdx.x;
  const int wave = __builtin_amdgcn_readfirstlane(tid >> 6);
  const int lane = tid & 63;
  const int lane15 = lane & 15;
  const int quad = lane >> 4;
  const int wm = wave >> 1;
  const int wn = wave & 1;
  const int n_blk = nt * 128;

  // ---- staging descriptors ----
  // A: 1 instr/thread: thread tid fills LDS elems [tid*8, tid*8+8) => row tid>>2, slot tid&3
  // B: 2 instrs/thread: rows (i*64 + tid>>2)
  const int su = ((tid & 3) ^ ((tid >> 3) & 3)) * 8;  // swizzled source elem offset
  const __hip_bfloat16* pa0;
  const __hip_bfloat16* pa1;
  {
    int r = tid >> 2;  // 0..63
    int lr = m_base + r;
    if (lr >= count) lr = count - 1;
    int t = idx[lr] & (TOT - 1);
    int rr = rows[lr];
    int b = t >> 12;  // L=4096
    int r0 = rr & (NCH - 1);
    int r1 = (rr >> 16) & (NCH - 1);
    pa0 = last_bf + (long long)(b * NCH + r0) * IDIM + su;
    pa1 = last_bf + (long long)(b * NCH + r1) * IDIM + su;
  }
  const __hip_bfloat16* pb[2];
#pragma unroll
  for (int i = 0; i < 2; ++i) {
    int rB = i * 64 + (tid >> 2);
    pb[i] = W_bf + (long long)(d * ODIM + n_blk + rB) * KDIM + su;
  }
  // wave-uniform LDS bases (global_load_lds dest = base + lane*16)
  const int aBase = wave * 512;             // elems: rows wave*16..+16
  const int bBase0 = wave * 512;            // B instr 0: rows wave*16..+16
  const int bBase1 = 2048 + wave * 512;     // B instr 1: rows 64+..

  floatx4 acc[2][4] = {};
  const int xcol = (quad ^ ((lane15 >> 1) & 3)) * 8;  // frag-read swizzled offset

  // prologue: stage chunk 0 into buf 0
  {
    async_copy16(pa0, &Als[0][aBase]);
    async_copy16(pb[0], &Bls[0][bBase0]);
    async_copy16(pb[1], &Bls[0][bBase1]);
  }

#pragma unroll
  for (int kt = 0; kt < 16; ++kt) {
    __syncthreads();  // chunk kt staged & visible; prior buf reads done
    if (kt < 15) {
      const int nb = (kt + 1) & 1;
      const int kn = kt + 1;
      const __hip_bfloat16* ga = (kn < 8) ? pa0 + kn * 32 : pa1 + (kn - 8) * 32;
      async_copy16(ga, &Als[nb][aBase]);
      async_copy16(pb[0] + kn * 32, &Bls[nb][bBase0]);
      async_copy16(pb[1] + kn * 32, &Bls[nb][bBase1]);
    }
    const int c = kt & 1;
    short8 a[2], b[4];
#pragma unroll
    for (int i = 0; i < 2; ++i)
      a[i] = *(const short8*)&Als[c][(wm * 32 + i * 16 + lane15) * 32 + xcol];
#pragma unroll
    for (int j = 0; j < 4; ++j)
      b[j] = *(const short8*)&Bls[c][(wn * 64 + j * 16 + lane15) * 32 + xcol];
#pragma unroll
    for (int i = 0; i < 2; ++i)
#pragma unroll
      for (int j = 0; j < 4; ++j)
        acc[i][j] = __builtin_amdgcn_mfma_f32_16x16x32_bf16(a[i], b[j], acc[i][j], 0, 0, 0);
  }

  // ---- epilogue: bias + leaky relu, scatter rows by token ----
  const float alpha = alpha_m[d];
  float bj[4];
#pragma unroll
  for (int j = 0; j < 4; ++j)
    bj[j] = bias[d * ODIM + n_blk + wn * 64 + j * 16 + lane15];

#pragma unroll
  for (int i = 0; i < 2; ++i) {
#pragma unroll
    for (int reg = 0; reg < 4; ++reg) {
      int row_id = m_base + wm * 32 + i * 16 + quad * 4 + reg;
      if (row_id >= count) continue;
      int t = idx[row_id] & (TOT - 1);
      float* orow = out + (long long)t * ODIM + n_blk + wn * 64;
#pragma unroll
      for (int j = 0; j < 4; ++j) {
        float y = acc[i][j][reg] + bj[j];
        y = y > 0.f ? y : alpha * y;
        orow[j * 16 + lane15] = y;
      }
    }
  }
}

extern "C" void kernel_launch(void* const* d_in, const int* in_sizes, int n_in,
                              void* d_out, int out_size, void* d_ws, size_t ws_size,
                              hipStream_t stream) {
  const float* last = (const float*)d_in[0];
  const float* W = (const float*)d_in[1];
  const float* bias = (const float*)d_in[2];
  const float* alpha = (const float*)d_in[3];
  const int* child_l = (const int*)d_in[4];
  const int* child_r = (const int*)d_in[5];
  const int* vec = (const int*)d_in[6];
  const int* drev = (const int*)d_in[7];
  const int* dmap = (const int*)d_in[8];

  int* ws = (int*)d_ws;

  hipMemsetAsync(ws, 0, 32, stream);
  scatter_kernel<<<TOT / 256, 256, 0, stream>>>(vec, child_l, child_r, drev, dmap, ws);
  prep_kernel<<<(N_LAST8 + N_W8) / 256, 256, 0, stream>>>(last, W, ws);
  // max m-tiles = TOT/MT + (NDIR-1) from per-dir padding
  dim3 grid(ODIM / 128, TOT / MT + NDIR, 1);
  gemm_kernel<<<grid, 256, 0, stream>>>(bias, alpha, ws, (float*)d_out);
}